// Round 1
// baseline (1607.563 us; speedup 1.0000x reference)
//
#include <hip/hip_runtime.h>
#include <hip/hip_bf16.h>
#include <cstddef>

// ---------------------------------------------------------------------------
// Problem dims (compile-time constants from the reference)
// ---------------------------------------------------------------------------
#define VOCAB 50000
#define EDIM  200
#define HDIM  128
#define BB 16
#define RR 10
#define SS 20
#define WW 64
#define NSENT (BB*RR*SS)   // 3200 word-level sequences
#define NREV  (BB*RR)      // 160 sentence-level sequences
#define G3    (3*HDIM)     // 384 gate rows per direction
#define NPROJ (2*G3)       // 768 (fwd+bwd concatenated)

// ---------------------------------------------------------------------------
// Generic tiled f32 GEMM:  C[M x 768] = A[M x K] @ [B0;B1]^T + [bias0;bias1]
//   B0,B1: each 384 x K row-major (gate weight matrices, fwd/bwd)
//   If A1 != nullptr, A row = 0.5*(A0 + A1)  (used for sent_rep = avg(hf,hb))
// Tile 64x64, 256 threads, 4x4 per thread, K-chunks of 32.
// ---------------------------------------------------------------------------
#define TS 64
#define KC 32

__global__ __launch_bounds__(256) void gemm2_bias(
    const float* __restrict__ A0, const float* __restrict__ A1,
    int M, int K,
    const float* __restrict__ B0, const float* __restrict__ B1,
    const float* __restrict__ bias0, const float* __restrict__ bias1,
    float* __restrict__ C)
{
    __shared__ __align__(16) float At[KC][TS + 4];
    __shared__ __align__(16) float Bt[KC][TS + 4];

    const int ct = blockIdx.x;            // 0..11 (col tiles over 768)
    const int rt = blockIdx.y;            // row tiles over M
    const int tid = threadIdx.x;
    const int r0 = (tid >> 4) << 2;       // 0,4,...,60
    const int c0 = (tid & 15) << 2;       // 0,4,...,60
    const int rowBase = rt * TS;
    const int colBase = ct * TS;

    const float* Bsrc = (colBase < G3) ? B0 : B1;
    const int bcolBase = (colBase < G3) ? colBase : (colBase - G3);

    float acc[4][4];
    #pragma unroll
    for (int i = 0; i < 4; ++i)
        #pragma unroll
        for (int j = 0; j < 4; ++j) acc[i][j] = 0.f;

    for (int k0 = 0; k0 < K; k0 += KC) {
        const int kc = min(KC, K - k0);
        // stage A chunk (transposed into LDS)
        for (int f = tid; f < TS * KC; f += 256) {
            int r = f >> 5;         // row within tile
            int k = f & 31;
            float v = 0.f;
            int row = rowBase + r;
            if (k < kc && row < M) {
                size_t idx = (size_t)row * K + k0 + k;
                v = A0[idx];
                if (A1) v = 0.5f * (v + A1[idx]);
            }
            At[k][r] = v;
        }
        // stage B chunk (transposed into LDS)
        for (int f = tid; f < TS * KC; f += 256) {
            int r = f >> 5;         // col within tile
            int k = f & 31;
            float v = 0.f;
            if (k < kc) v = Bsrc[(size_t)(bcolBase + r) * K + k0 + k];
            Bt[k][r] = v;
        }
        __syncthreads();
        #pragma unroll 8
        for (int k = 0; k < kc; ++k) {
            float4 av = *(const float4*)&At[k][r0];
            float4 bv = *(const float4*)&Bt[k][c0];
            acc[0][0] = fmaf(av.x, bv.x, acc[0][0]);
            acc[0][1] = fmaf(av.x, bv.y, acc[0][1]);
            acc[0][2] = fmaf(av.x, bv.z, acc[0][2]);
            acc[0][3] = fmaf(av.x, bv.w, acc[0][3]);
            acc[1][0] = fmaf(av.y, bv.x, acc[1][0]);
            acc[1][1] = fmaf(av.y, bv.y, acc[1][1]);
            acc[1][2] = fmaf(av.y, bv.z, acc[1][2]);
            acc[1][3] = fmaf(av.y, bv.w, acc[1][3]);
            acc[2][0] = fmaf(av.z, bv.x, acc[2][0]);
            acc[2][1] = fmaf(av.z, bv.y, acc[2][1]);
            acc[2][2] = fmaf(av.z, bv.z, acc[2][2]);
            acc[2][3] = fmaf(av.z, bv.w, acc[2][3]);
            acc[3][0] = fmaf(av.w, bv.x, acc[3][0]);
            acc[3][1] = fmaf(av.w, bv.y, acc[3][1]);
            acc[3][2] = fmaf(av.w, bv.z, acc[3][2]);
            acc[3][3] = fmaf(av.w, bv.w, acc[3][3]);
        }
        __syncthreads();
    }

    const float* bsrc = (colBase < G3) ? bias0 : bias1;
    #pragma unroll
    for (int i = 0; i < 4; ++i) {
        int row = rowBase + r0 + i;
        if (row < M) {
            float* cp = C + (size_t)row * NPROJ + colBase + c0;
            #pragma unroll
            for (int j = 0; j < 4; ++j)
                cp[j] = acc[i][j] + bsrc[bcolBase + c0 + j];
        }
    }
}

// ---------------------------------------------------------------------------
// GRU scan kernel (both word-level and sentence-level via template).
// Grid: 2*numTiles blocks (first half dir=fwd, second half dir=bwd).
// Block: 384 threads; thread o owns gate-output row o, persists Whh[o,:] in
// 128 VGPRs. h lives in LDS; broadcast float4 reads feed the per-seq dot.
// Early-exit semantics: forward processes t=0..len-1; backward processes
// original indices len-1..0 (equivalent to the reference's masked scan).
// ---------------------------------------------------------------------------
template<int NSEQ, bool WORD, int TMAX>
__global__ __launch_bounds__(384) void gru_scan(
    const float* __restrict__ table,    // [*, 768] projected-input table
    const int*   __restrict__ tokens,   // word-level: [numSeq*WW]; else unused
    const int*   __restrict__ lengths,  // [numSeq]
    const float* __restrict__ Whh_f, const float* __restrict__ Whh_b,
    const float* __restrict__ bhh_f, const float* __restrict__ bhh_b,
    float* __restrict__ hout_f, float* __restrict__ hout_b,
    int numSeq, int numTiles)
{
    const int dir  = (blockIdx.x >= numTiles) ? 1 : 0;
    const int tile = dir ? (blockIdx.x - numTiles) : blockIdx.x;
    const int base = tile * NSEQ;
    const int o = threadIdx.x;          // 0..383

    const float* Whh = dir ? Whh_b : Whh_f;
    float w[128];
    #pragma unroll
    for (int i = 0; i < 32; ++i) {
        float4 v = *(const float4*)(Whh + (size_t)o * HDIM + i * 4);
        w[4*i+0] = v.x; w[4*i+1] = v.y; w[4*i+2] = v.z; w[4*i+3] = v.w;
    }
    const float bhh_r = (dir ? bhh_b : bhh_f)[o];

    __shared__ __align__(16) float sh_h[NSEQ][HDIM];
    __shared__ float sh_hg[NSEQ][G3];
    __shared__ int sh_len[NSEQ];
    __shared__ int sh_tok[WORD ? NSEQ * WW : 1];

    if (o < NSEQ) {
        int seq = base + o;
        sh_len[o] = (seq < numSeq) ? lengths[seq] : 0;
    }
    if (WORD) {
        for (int f = o; f < NSEQ * WW; f += 384) {
            int s = f / WW;
            int seq = base + s;
            sh_tok[f] = (seq < numSeq) ? tokens[(size_t)seq * WW + (f % WW)] : 0;
        }
    }
    for (int u = o; u < NSEQ * HDIM; u += 384)
        sh_h[u >> 7][u & 127] = 0.f;
    __syncthreads();

    int maxlen = 0;
    #pragma unroll
    for (int s = 0; s < NSEQ; ++s) maxlen = max(maxlen, sh_len[s]);

    for (int t = 0; t < maxlen; ++t) {
        // --- hg = Whh @ h + bhh, per active sequence (uniform branch) ---
        for (int s = 0; s < NSEQ; ++s) {
            if (t < sh_len[s]) {
                const float4* h4 = (const float4*)(&sh_h[s][0]);
                float a0 = 0.f, a1 = 0.f, a2 = 0.f, a3 = 0.f;
                #pragma unroll
                for (int i = 0; i < 32; ++i) {
                    float4 hv = h4[i];
                    a0 = fmaf(w[4*i+0], hv.x, a0);
                    a1 = fmaf(w[4*i+1], hv.y, a1);
                    a2 = fmaf(w[4*i+2], hv.z, a2);
                    a3 = fmaf(w[4*i+3], hv.w, a3);
                }
                sh_hg[s][o] = ((a0 + a1) + (a2 + a3)) + bhh_r;
            }
        }
        __syncthreads();
        // --- gate update: one thread per (seq, hidden-elem) ---
        for (int u = o; u < NSEQ * HDIM; u += 384) {
            int s = u >> 7, e = u & 127;
            int len = sh_len[s];
            if (t < len) {
                int tt = dir ? (len - 1 - t) : t;
                size_t row;
                if (WORD) row = (size_t)sh_tok[s * WW + tt];
                else      row = (size_t)(base + s) * TMAX + tt;
                const float* xg = table + row * NPROJ + dir * G3 + e;
                float xr = xg[0], xz = xg[HDIM], xn = xg[2*HDIM];
                float hgr = sh_hg[s][e];
                float hgz = sh_hg[s][HDIM + e];
                float hgn = sh_hg[s][2*HDIM + e];
                float hold = sh_h[s][e];
                float r = 1.f / (1.f + expf(-(xr + hgr)));
                float z = 1.f / (1.f + expf(-(xz + hgz)));
                float n = tanhf(xn + r * hgn);
                sh_h[s][e] = (1.f - z) * n + z * hold;
            }
        }
        __syncthreads();
    }

    float* hout = dir ? hout_b : hout_f;
    for (int u = o; u < NSEQ * HDIM; u += 384) {
        int s = u >> 7, e = u & 127;
        int seq = base + s;
        if (seq < numSeq) hout[(size_t)seq * HDIM + e] = sh_h[s][e];
    }
}

// ---------------------------------------------------------------------------
// Head: rev = 0.5*(hsf+hsb); h1 = selu(rev @ fc1^T + b1); r = h1 @ fc2^T + b2
// One block (64 threads) per (b,r). Writes r_stars to out[16..176).
// ---------------------------------------------------------------------------
__global__ __launch_bounds__(64) void head_kernel(
    const float* __restrict__ hsf, const float* __restrict__ hsb,
    const float* __restrict__ fc1_w, const float* __restrict__ fc1_b,
    const float* __restrict__ fc2_w, const float* __restrict__ fc2_b,
    float* __restrict__ out)
{
    const int br = blockIdx.x;     // 0..159
    const int j = threadIdx.x;     // 0..63
    __shared__ float rev[HDIM];
    for (int e = j; e < HDIM; e += 64)
        rev[e] = 0.5f * (hsf[(size_t)br * HDIM + e] + hsb[(size_t)br * HDIM + e]);
    __syncthreads();
    float acc = 0.f;
    #pragma unroll
    for (int k = 0; k < HDIM; ++k)
        acc = fmaf(fc1_w[(size_t)j * HDIM + k], rev[k], acc);
    acc += fc1_b[j];
    const float alpha = 1.6732632423543772f;
    const float scale = 1.0507009873554805f;
    float h1 = scale * (acc > 0.f ? acc : alpha * (expf(acc) - 1.f));
    float contrib = h1 * fc2_w[j];
    #pragma unroll
    for (int off = 32; off > 0; off >>= 1)
        contrib += __shfl_down(contrib, off);
    if (j == 0) out[16 + br] = contrib + fc2_b[0];
}

// p_stars[b] = mean over r of r_stars[b, r]
__global__ void mean_kernel(float* __restrict__ out)
{
    int b = threadIdx.x;
    if (b < BB) {
        float s = 0.f;
        for (int r = 0; r < RR; ++r) s += out[16 + b * RR + r];
        out[b] = s / (float)RR;
    }
}

// ---------------------------------------------------------------------------
// Launch
// ---------------------------------------------------------------------------
extern "C" void kernel_launch(void* const* d_in, const int* in_sizes, int n_in,
                              void* d_out, int out_size, void* d_ws, size_t ws_size,
                              hipStream_t stream)
{
    const int*   inputs       = (const int*)d_in[0];
    const int*   sent_lengths = (const int*)d_in[1];
    const int*   sent_counts  = (const int*)d_in[2];
    const float* embed   = (const float*)d_in[3];
    const float* wWih_f  = (const float*)d_in[4];
    const float* wWhh_f  = (const float*)d_in[5];
    const float* wbih_f  = (const float*)d_in[6];
    const float* wbhh_f  = (const float*)d_in[7];
    const float* wWih_b  = (const float*)d_in[8];
    const float* wWhh_b  = (const float*)d_in[9];
    const float* wbih_b  = (const float*)d_in[10];
    const float* wbhh_b  = (const float*)d_in[11];
    const float* sWih_f  = (const float*)d_in[12];
    const float* sWhh_f  = (const float*)d_in[13];
    const float* sbih_f  = (const float*)d_in[14];
    const float* sbhh_f  = (const float*)d_in[15];
    const float* sWih_b  = (const float*)d_in[16];
    const float* sWhh_b  = (const float*)d_in[17];
    const float* sbih_b  = (const float*)d_in[18];
    const float* sbhh_b  = (const float*)d_in[19];
    const float* fc1_w   = (const float*)d_in[20];
    const float* fc1_b   = (const float*)d_in[21];
    const float* fc2_w   = (const float*)d_in[22];
    const float* fc2_b   = (const float*)d_in[23];

    float* ws = (float*)d_ws;
    // workspace layout (f32 elements)
    const size_t projT_elems = (size_t)VOCAB * NPROJ;      // 38,400,000
    const size_t xgs_elems   = (size_t)NSENT * NPROJ;      //  2,457,600
    const size_t h_elems     = (size_t)NSENT * HDIM;       //    409,600
    const size_t hs_elems    = (size_t)NREV * HDIM;        //     20,480
    float* projT = ws;
    float* xgs   = projT + projT_elems;
    float* hf    = xgs + xgs_elems;
    float* hb    = hf + h_elems;
    float* hsf   = hb + h_elems;
    float* hsb   = hsf + hs_elems;

    size_t need = (projT_elems + xgs_elems + 2*h_elems + 2*hs_elems) * sizeof(float);
    if (ws_size < need) return;   // cannot run without scratch

    // 1) projected-embedding table: projT[v] = [wWih_f; wWih_b] @ embed[v] + bih
    {
        dim3 grid(NPROJ / TS, (VOCAB + TS - 1) / TS);   // 12 x 782
        gemm2_bias<<<grid, 256, 0, stream>>>(
            embed, nullptr, VOCAB, EDIM,
            wWih_f, wWih_b, wbih_f, wbih_b, projT);
    }
    // 2) word-level BiGRU last-h (both directions in one grid)
    {
        constexpr int NSEQ = 8;
        int numTiles = NSENT / NSEQ;                    // 400
        gru_scan<NSEQ, true, WW><<<2 * numTiles, 384, 0, stream>>>(
            projT, inputs, sent_lengths,
            wWhh_f, wWhh_b, wbhh_f, wbhh_b,
            hf, hb, NSENT, numTiles);
    }
    // 3) sentence-level input projections: xgs = (0.5*(hf+hb)) @ [sWih_f;sWih_b]^T + sbih
    {
        dim3 grid(NPROJ / TS, NSENT / TS);              // 12 x 50
        gemm2_bias<<<grid, 256, 0, stream>>>(
            hf, hb, NSENT, HDIM,
            sWih_f, sWih_b, sbih_f, sbih_b, xgs);
    }
    // 4) sentence-level BiGRU last-h
    {
        constexpr int NSEQ = 4;
        int numTiles = NREV / NSEQ;                     // 40
        gru_scan<NSEQ, false, SS><<<2 * numTiles, 384, 0, stream>>>(
            xgs, nullptr, sent_counts,
            sWhh_f, sWhh_b, sbhh_f, sbhh_b,
            hsf, hsb, NREV, numTiles);
    }
    // 5) FC head -> r_stars, then p_stars
    head_kernel<<<NREV, 64, 0, stream>>>(hsf, hsb, fc1_w, fc1_b, fc2_w, fc2_b,
                                         (float*)d_out);
    mean_kernel<<<1, 64, 0, stream>>>((float*)d_out);
}

// Round 2
// 1057.094 us; speedup vs baseline: 1.5207x; 1.5207x over previous
//
#include <hip/hip_runtime.h>
#include <hip/hip_bf16.h>
#include <cstddef>

// ---------------------------------------------------------------------------
// Problem dims (compile-time constants from the reference)
// ---------------------------------------------------------------------------
#define VOCAB 50000
#define EDIM  200
#define HDIM  128
#define BB 16
#define RR 10
#define SS 20
#define WW 64
#define NSENT (BB*RR*SS)   // 3200 word-level sequences
#define NREV  (BB*RR)      // 160 sentence-level sequences
#define G3    (3*HDIM)     // 384 gate rows per direction
#define NPROJ (2*G3)       // 768 (fwd+bwd concatenated)

// ---------------------------------------------------------------------------
// Generic tiled f32 GEMM:  C[M x 768] = A[M x K] @ [B0;B1]^T + [bias0;bias1]
//   B0,B1: each 384 x K row-major (gate weight matrices, fwd/bwd)
//   If A1 != nullptr, A row = 0.5*(A0 + A1)  (used for sent_rep = avg(hf,hb))
// Tile 64x64, 256 threads, 4x4 per thread, K-chunks of 32.
// ---------------------------------------------------------------------------
#define TS 64
#define KC 32

__global__ __launch_bounds__(256) void gemm2_bias(
    const float* __restrict__ A0, const float* __restrict__ A1,
    int M, int K,
    const float* __restrict__ B0, const float* __restrict__ B1,
    const float* __restrict__ bias0, const float* __restrict__ bias1,
    float* __restrict__ C)
{
    __shared__ __align__(16) float At[KC][TS + 4];
    __shared__ __align__(16) float Bt[KC][TS + 4];

    const int ct = blockIdx.x;            // 0..11 (col tiles over 768)
    const int rt = blockIdx.y;            // row tiles over M
    const int tid = threadIdx.x;
    const int r0 = (tid >> 4) << 2;       // 0,4,...,60
    const int c0 = (tid & 15) << 2;       // 0,4,...,60
    const int rowBase = rt * TS;
    const int colBase = ct * TS;

    const float* Bsrc = (colBase < G3) ? B0 : B1;
    const int bcolBase = (colBase < G3) ? colBase : (colBase - G3);

    float acc[4][4];
    #pragma unroll
    for (int i = 0; i < 4; ++i)
        #pragma unroll
        for (int j = 0; j < 4; ++j) acc[i][j] = 0.f;

    for (int k0 = 0; k0 < K; k0 += KC) {
        const int kc = min(KC, K - k0);
        // stage A chunk (transposed into LDS)
        for (int f = tid; f < TS * KC; f += 256) {
            int r = f >> 5;         // row within tile
            int k = f & 31;
            float v = 0.f;
            int row = rowBase + r;
            if (k < kc && row < M) {
                size_t idx = (size_t)row * K + k0 + k;
                v = A0[idx];
                if (A1) v = 0.5f * (v + A1[idx]);
            }
            At[k][r] = v;
        }
        // stage B chunk (transposed into LDS)
        for (int f = tid; f < TS * KC; f += 256) {
            int r = f >> 5;         // col within tile
            int k = f & 31;
            float v = 0.f;
            if (k < kc) v = Bsrc[(size_t)(bcolBase + r) * K + k0 + k];
            Bt[k][r] = v;
        }
        __syncthreads();
        #pragma unroll 8
        for (int k = 0; k < kc; ++k) {
            float4 av = *(const float4*)&At[k][r0];
            float4 bv = *(const float4*)&Bt[k][c0];
            acc[0][0] = fmaf(av.x, bv.x, acc[0][0]);
            acc[0][1] = fmaf(av.x, bv.y, acc[0][1]);
            acc[0][2] = fmaf(av.x, bv.z, acc[0][2]);
            acc[0][3] = fmaf(av.x, bv.w, acc[0][3]);
            acc[1][0] = fmaf(av.y, bv.x, acc[1][0]);
            acc[1][1] = fmaf(av.y, bv.y, acc[1][1]);
            acc[1][2] = fmaf(av.y, bv.z, acc[1][2]);
            acc[1][3] = fmaf(av.y, bv.w, acc[1][3]);
            acc[2][0] = fmaf(av.z, bv.x, acc[2][0]);
            acc[2][1] = fmaf(av.z, bv.y, acc[2][1]);
            acc[2][2] = fmaf(av.z, bv.z, acc[2][2]);
            acc[2][3] = fmaf(av.z, bv.w, acc[2][3]);
            acc[3][0] = fmaf(av.w, bv.x, acc[3][0]);
            acc[3][1] = fmaf(av.w, bv.y, acc[3][1]);
            acc[3][2] = fmaf(av.w, bv.z, acc[3][2]);
            acc[3][3] = fmaf(av.w, bv.w, acc[3][3]);
        }
        __syncthreads();
    }

    const float* bsrc = (colBase < G3) ? bias0 : bias1;
    #pragma unroll
    for (int i = 0; i < 4; ++i) {
        int row = rowBase + r0 + i;
        if (row < M) {
            float* cp = C + (size_t)row * NPROJ + colBase + c0;
            #pragma unroll
            for (int j = 0; j < 4; ++j)
                cp[j] = acc[i][j] + bsrc[bcolBase + c0 + j];
        }
    }
}

// ---------------------------------------------------------------------------
// GRU scan kernel, k-split-2 layout.
// Grid: 2*numTiles blocks (first half dir=fwd, second half dir=bwd).
// Block: 768 threads = (row o in [0,384)) x (k-half in {0,1}).
// Thread (o,half) persists Whh[o, half*64 .. half*64+63] in 64 regs and
// writes a partial dot to sh_hgp[half][s][o]; the gate phase (1 elem/thread,
// s_g = tid>>7, e_g = tid&127) sums both halves. The projected-table gather
// for step t is prefetched into registers at the top of step t so its
// latency hides under the hg FMA phase.
// ---------------------------------------------------------------------------
template<int NSEQ, bool WORD, int TMAX>
__global__ __launch_bounds__(768, 3) void gru_scan(
    const float* __restrict__ table,    // [*, 768] projected-input table
    const int*   __restrict__ tokens,   // word-level: [numSeq*WW]; else unused
    const int*   __restrict__ lengths,  // [numSeq]
    const float* __restrict__ Whh_f, const float* __restrict__ Whh_b,
    const float* __restrict__ bhh_f, const float* __restrict__ bhh_b,
    float* __restrict__ hout_f, float* __restrict__ hout_b,
    int numSeq, int numTiles)
{
    const int dir  = (blockIdx.x >= numTiles) ? 1 : 0;
    const int tile = dir ? (blockIdx.x - numTiles) : blockIdx.x;
    const int base = tile * NSEQ;
    const int tid = threadIdx.x;        // 0..767
    const int half = (tid >= 384) ? 1 : 0;   // wave-uniform (384 = 6*64)
    const int o = tid - half * 384;     // 0..383

    const float* Whh = dir ? Whh_b : Whh_f;
    float w[64];
    #pragma unroll
    for (int i = 0; i < 16; ++i) {
        float4 v = *(const float4*)(Whh + (size_t)o * HDIM + half * 64 + i * 4);
        w[4*i+0] = v.x; w[4*i+1] = v.y; w[4*i+2] = v.z; w[4*i+3] = v.w;
    }
    const float bhh_r = half ? 0.f : (dir ? bhh_b : bhh_f)[o];

    __shared__ __align__(16) float sh_h[NSEQ][HDIM];
    __shared__ float sh_hgp[2][NSEQ][G3];
    __shared__ int sh_len[NSEQ];
    __shared__ int sh_tok[WORD ? NSEQ * WW : 1];

    if (tid < NSEQ) {
        int seq = base + tid;
        sh_len[tid] = (seq < numSeq) ? lengths[seq] : 0;
    }
    if (WORD) {
        for (int f = tid; f < NSEQ * WW; f += 768) {
            int s = f / WW;
            int seq = base + s;
            sh_tok[f] = (seq < numSeq) ? tokens[(size_t)seq * WW + (f % WW)] : 0;
        }
    }
    for (int u = tid; u < NSEQ * HDIM; u += 768)
        sh_h[u >> 7][u & 127] = 0.f;
    __syncthreads();

    // per-thread copies of lengths (constant indices after unroll -> regs)
    int lenreg[NSEQ];
    int maxlen = 0;
    #pragma unroll
    for (int s = 0; s < NSEQ; ++s) {
        lenreg[s] = sh_len[s];
        maxlen = max(maxlen, lenreg[s]);
    }

    // gate-phase mapping: exactly one (seq, elem) per thread (NSEQ*128 == 768)
    const int s_g = tid >> 7;           // 0..NSEQ-1
    const int e_g = tid & 127;
    const int len_g = sh_len[s_g];      // LDS read once (dynamic index)

    for (int t = 0; t < maxlen; ++t) {
        // ---- prefetch this step's xg gather into registers ----
        float pr = 0.f, pz = 0.f, pn = 0.f;
        const bool act_g = (t < len_g);
        if (act_g) {
            int tt = dir ? (len_g - 1 - t) : t;
            size_t row;
            if (WORD) row = (size_t)sh_tok[s_g * WW + tt];
            else      row = (size_t)(base + s_g) * TMAX + tt;
            const float* xg = table + row * NPROJ + dir * G3 + e_g;
            pr = xg[0]; pz = xg[HDIM]; pn = xg[2*HDIM];
        }
        // ---- hg partial: half-dot over 64 h-elems, per active sequence ----
        #pragma unroll
        for (int s = 0; s < NSEQ; ++s) {
            if (t < lenreg[s]) {        // wave-uniform branch
                const float4* h4 = (const float4*)(&sh_h[s][half * 64]);
                float a0 = 0.f, a1 = 0.f, a2 = 0.f, a3 = 0.f;
                #pragma unroll
                for (int i = 0; i < 16; ++i) {
                    float4 hv = h4[i];
                    a0 = fmaf(w[4*i+0], hv.x, a0);
                    a1 = fmaf(w[4*i+1], hv.y, a1);
                    a2 = fmaf(w[4*i+2], hv.z, a2);
                    a3 = fmaf(w[4*i+3], hv.w, a3);
                }
                sh_hgp[half][s][o] = ((a0 + a1) + (a2 + a3)) + bhh_r;
            }
        }
        __syncthreads();
        // ---- gate update: one (seq, elem) per thread ----
        if (act_g) {
            float hgr = sh_hgp[0][s_g][e_g]          + sh_hgp[1][s_g][e_g];
            float hgz = sh_hgp[0][s_g][e_g + HDIM]   + sh_hgp[1][s_g][e_g + HDIM];
            float hgn = sh_hgp[0][s_g][e_g + 2*HDIM] + sh_hgp[1][s_g][e_g + 2*HDIM];
            float hold = sh_h[s_g][e_g];
            float r = 1.f / (1.f + expf(-(pr + hgr)));
            float z = 1.f / (1.f + expf(-(pz + hgz)));
            float n = tanhf(pn + r * hgn);
            sh_h[s_g][e_g] = (1.f - z) * n + z * hold;
        }
        __syncthreads();
    }

    float* hout = dir ? hout_b : hout_f;
    for (int u = tid; u < NSEQ * HDIM; u += 768) {
        int s = u >> 7, e = u & 127;
        int seq = base + s;
        if (seq < numSeq) hout[(size_t)seq * HDIM + e] = sh_h[s][e];
    }
}

// ---------------------------------------------------------------------------
// Head: rev = 0.5*(hsf+hsb); h1 = selu(rev @ fc1^T + b1); r = h1 @ fc2^T + b2
// One block (64 threads) per (b,r). Writes r_stars to out[16..176).
// ---------------------------------------------------------------------------
__global__ __launch_bounds__(64) void head_kernel(
    const float* __restrict__ hsf, const float* __restrict__ hsb,
    const float* __restrict__ fc1_w, const float* __restrict__ fc1_b,
    const float* __restrict__ fc2_w, const float* __restrict__ fc2_b,
    float* __restrict__ out)
{
    const int br = blockIdx.x;     // 0..159
    const int j = threadIdx.x;     // 0..63
    __shared__ float rev[HDIM];
    for (int e = j; e < HDIM; e += 64)
        rev[e] = 0.5f * (hsf[(size_t)br * HDIM + e] + hsb[(size_t)br * HDIM + e]);
    __syncthreads();
    float acc = 0.f;
    #pragma unroll
    for (int k = 0; k < HDIM; ++k)
        acc = fmaf(fc1_w[(size_t)j * HDIM + k], rev[k], acc);
    acc += fc1_b[j];
    const float alpha = 1.6732632423543772f;
    const float scale = 1.0507009873554805f;
    float h1 = scale * (acc > 0.f ? acc : alpha * (expf(acc) - 1.f));
    float contrib = h1 * fc2_w[j];
    #pragma unroll
    for (int off = 32; off > 0; off >>= 1)
        contrib += __shfl_down(contrib, off);
    if (j == 0) out[16 + br] = contrib + fc2_b[0];
}

// p_stars[b] = mean over r of r_stars[b, r]
__global__ void mean_kernel(float* __restrict__ out)
{
    int b = threadIdx.x;
    if (b < BB) {
        float s = 0.f;
        for (int r = 0; r < RR; ++r) s += out[16 + b * RR + r];
        out[b] = s / (float)RR;
    }
}

// ---------------------------------------------------------------------------
// Launch
// ---------------------------------------------------------------------------
extern "C" void kernel_launch(void* const* d_in, const int* in_sizes, int n_in,
                              void* d_out, int out_size, void* d_ws, size_t ws_size,
                              hipStream_t stream)
{
    const int*   inputs       = (const int*)d_in[0];
    const int*   sent_lengths = (const int*)d_in[1];
    const int*   sent_counts  = (const int*)d_in[2];
    const float* embed   = (const float*)d_in[3];
    const float* wWih_f  = (const float*)d_in[4];
    const float* wWhh_f  = (const float*)d_in[5];
    const float* wbih_f  = (const float*)d_in[6];
    const float* wbhh_f  = (const float*)d_in[7];
    const float* wWih_b  = (const float*)d_in[8];
    const float* wWhh_b  = (const float*)d_in[9];
    const float* wbih_b  = (const float*)d_in[10];
    const float* wbhh_b  = (const float*)d_in[11];
    const float* sWih_f  = (const float*)d_in[12];
    const float* sWhh_f  = (const float*)d_in[13];
    const float* sbih_f  = (const float*)d_in[14];
    const float* sbhh_f  = (const float*)d_in[15];
    const float* sWih_b  = (const float*)d_in[16];
    const float* sWhh_b  = (const float*)d_in[17];
    const float* sbih_b  = (const float*)d_in[18];
    const float* sbhh_b  = (const float*)d_in[19];
    const float* fc1_w   = (const float*)d_in[20];
    const float* fc1_b   = (const float*)d_in[21];
    const float* fc2_w   = (const float*)d_in[22];
    const float* fc2_b   = (const float*)d_in[23];

    float* ws = (float*)d_ws;
    // workspace layout (f32 elements)
    const size_t projT_elems = (size_t)VOCAB * NPROJ;      // 38,400,000
    const size_t xgs_elems   = (size_t)NSENT * NPROJ;      //  2,457,600
    const size_t h_elems     = (size_t)NSENT * HDIM;       //    409,600
    const size_t hs_elems    = (size_t)NREV * HDIM;        //     20,480
    float* projT = ws;
    float* xgs   = projT + projT_elems;
    float* hf    = xgs + xgs_elems;
    float* hb    = hf + h_elems;
    float* hsf   = hb + h_elems;
    float* hsb   = hsf + hs_elems;

    size_t need = (projT_elems + xgs_elems + 2*h_elems + 2*hs_elems) * sizeof(float);
    if (ws_size < need) return;   // cannot run without scratch

    // 1) projected-embedding table: projT[v] = [wWih_f; wWih_b] @ embed[v] + bih
    {
        dim3 grid(NPROJ / TS, (VOCAB + TS - 1) / TS);   // 12 x 782
        gemm2_bias<<<grid, 256, 0, stream>>>(
            embed, nullptr, VOCAB, EDIM,
            wWih_f, wWih_b, wbih_f, wbih_b, projT);
    }
    // 2) word-level BiGRU last-h (both directions in one grid)
    {
        constexpr int NSEQ = 6;
        int numTiles = (NSENT + NSEQ - 1) / NSEQ;       // 534
        gru_scan<NSEQ, true, WW><<<2 * numTiles, 768, 0, stream>>>(
            projT, inputs, sent_lengths,
            wWhh_f, wWhh_b, wbhh_f, wbhh_b,
            hf, hb, NSENT, numTiles);
    }
    // 3) sentence-level input projections: xgs = (0.5*(hf+hb)) @ [sWih_f;sWih_b]^T + sbih
    {
        dim3 grid(NPROJ / TS, NSENT / TS);              // 12 x 50
        gemm2_bias<<<grid, 256, 0, stream>>>(
            hf, hb, NSENT, HDIM,
            sWih_f, sWih_b, sbih_f, sbih_b, xgs);
    }
    // 4) sentence-level BiGRU last-h
    {
        constexpr int NSEQ = 6;
        int numTiles = (NREV + NSEQ - 1) / NSEQ;        // 27
        gru_scan<NSEQ, false, SS><<<2 * numTiles, 768, 0, stream>>>(
            xgs, nullptr, sent_counts,
            sWhh_f, sWhh_b, sbhh_f, sbhh_b,
            hsf, hsb, NREV, numTiles);
    }
    // 5) FC head -> r_stars, then p_stars
    head_kernel<<<NREV, 64, 0, stream>>>(hsf, hsb, fc1_w, fc1_b, fc2_w, fc2_b,
                                         (float*)d_out);
    mean_kernel<<<1, 64, 0, stream>>>((float*)d_out);
}